// Round 3
// baseline (279.062 us; speedup 1.0000x reference)
//
#include <hip/hip_runtime.h>
#include <math.h>

#define L    1024
#define D    256
#define NCH  3
#define HEADS 32      // B*N
#define EDIM 112
#define BATCH 4

typedef __bf16 bf8_t __attribute__((ext_vector_type(8)));
typedef float  f4_t  __attribute__((ext_vector_type(4)));

// RNE float->bf16
__device__ inline unsigned short f2bf(float x) {
    unsigned u = __float_as_uint(x);
    u += 0x7FFFu + ((u >> 16) & 1u);
    return (unsigned short)(u >> 16);
}
__device__ inline float bf2f(unsigned short h) {
    return __uint_as_float(((unsigned)h) << 16);
}

// ---------------- fused prologue: pe_d + edge + xs -------------------------
__global__ void prep_kernel(const float* __restrict__ edge, const float* __restrict__ xi,
                            float* __restrict__ pe_d, float* __restrict__ eout,
                            float* __restrict__ xsb)
{
    int idx = blockIdx.x * blockDim.x + threadIdx.x;
    if (idx < L * D) {
        int l = idx >> 8, i = idx & (D - 1);
        float expo = (float)(i & ~1) * (1.0f / (float)D);
        float ang = (float)l * __powf(10000.0f, -expo);
        pe_d[idx] = (i & 1) ? cosf(ang) : sinf(ang);
    } else if (idx < L * D + BATCH * L * EDIM) {
        int j = idx - L * D;
        int i = j % EDIM;
        int l = (j / EDIM) % L;
        float expo = (float)(i & ~1) * (1.0f / (float)EDIM);
        float ang = (float)l * __powf(10000.0f, -expo);
        eout[j] = edge[j] + ((i & 1) ? cosf(ang) : sinf(ang));
    } else {
        int j = idx - (L * D + BATCH * L * EDIM);
        if (j < HEADS * L * NCH) {
            int c = j % 3;
            int l = (j / 3) & (L - 1);
            float ang = (c == 2) ? (float)l * 0.0021544347f : (float)l;  // 10000^(-2/3)
            float pe = (c == 1) ? cosf(ang) : sinf(ang);
            xsb[j] = xi[j] + pe;
        }
    }
}

// ---------------- QKV projection via split-bf16 MFMA (2-term) --------------
__global__ __launch_bounds__(256) void qkv_mfma(
    const float* __restrict__ theta, const float* __restrict__ pe_d,
    const float* __restrict__ Wq, const float* __restrict__ Wk, const float* __restrict__ Wv,
    unsigned short* __restrict__ qh, unsigned short* __restrict__ ql,
    unsigned short* __restrict__ kh, unsigned short* __restrict__ vt)
{
    __shared__ unsigned short XsH[128][40], XsL[128][40], WsH[128][40];

    int tid = threadIdx.x;
    int w = tid >> 6, lane = tid & 63;
    int quad = lane >> 4, l16 = lane & 15;
    int aoff = (w & 1) * 64, boff = (w >> 1) * 64;

    int b = blockIdx.x;                 // 0..1535
    int xcd = b & 7, r = b >> 3;        // r in 0..191
    int bx = r % 6;                     // selector (wsel, eBase)
    int rowPanel = (r / 6) * 8 + xcd;   // 0..255, all 6 bx of a panel share xcd
    int rowBase = rowPanel * 128;
    int wsel = bx >> 1;
    int eBase = (bx & 1) * 128;
    const float* W = (wsel == 0) ? Wq : (wsel == 1) ? Wk : Wv;

    f4_t acc[4][4];
    #pragma unroll
    for (int mi = 0; mi < 4; mi++)
        #pragma unroll
        for (int ni = 0; ni < 4; ni++) acc[mi][ni] = (f4_t){0.f, 0.f, 0.f, 0.f};

    int sr = tid >> 1;
    int ks = (tid & 1) * 16;

    for (int kt = 0; kt < 8; kt++) {
        int k0 = kt * 32 + ks;
        __syncthreads();
        {
            union { unsigned short us[16]; float4 f4[2]; } hi, lo;
            const float* tp = &theta[(size_t)(rowBase + sr) * D + k0];
            const float* pp = &pe_d[(size_t)((rowBase + sr) & (L - 1)) * D + k0];
            #pragma unroll
            for (int j = 0; j < 4; j++) {
                float4 tv = reinterpret_cast<const float4*>(tp)[j];
                float4 pv = reinterpret_cast<const float4*>(pp)[j];
                float xs[4] = {tv.x + pv.x, tv.y + pv.y, tv.z + pv.z, tv.w + pv.w};
                #pragma unroll
                for (int q = 0; q < 4; q++) {
                    unsigned short h = f2bf(xs[q]);
                    hi.us[j * 4 + q] = h;
                    lo.us[j * 4 + q] = f2bf(xs[q] - bf2f(h));
                }
            }
            *reinterpret_cast<float4*>(&XsH[sr][ks]) = hi.f4[0];
            *reinterpret_cast<float4*>(&XsH[sr][ks + 8]) = hi.f4[1];
            *reinterpret_cast<float4*>(&XsL[sr][ks]) = lo.f4[0];
            *reinterpret_cast<float4*>(&XsL[sr][ks + 8]) = lo.f4[1];

            const float* wp = &W[(size_t)(eBase + sr) * D + k0];
            #pragma unroll
            for (int j = 0; j < 4; j++) {
                float4 wv = reinterpret_cast<const float4*>(wp)[j];
                float xs[4] = {wv.x, wv.y, wv.z, wv.w};
                #pragma unroll
                for (int q = 0; q < 4; q++) hi.us[j * 4 + q] = f2bf(xs[q]);
            }
            *reinterpret_cast<float4*>(&WsH[sr][ks]) = hi.f4[0];
            *reinterpret_cast<float4*>(&WsH[sr][ks + 8]) = hi.f4[1];
        }
        __syncthreads();

        if (wsel < 2) {
            bf8_t aw[4];
            #pragma unroll
            for (int mi = 0; mi < 4; mi++)
                aw[mi] = *reinterpret_cast<const bf8_t*>(&WsH[aoff + mi * 16 + l16][quad * 8]);
            #pragma unroll
            for (int ni = 0; ni < 4; ni++) {
                bf8_t bxh = *reinterpret_cast<const bf8_t*>(&XsH[boff + ni * 16 + l16][quad * 8]);
                bf8_t bxl = *reinterpret_cast<const bf8_t*>(&XsL[boff + ni * 16 + l16][quad * 8]);
                #pragma unroll
                for (int mi = 0; mi < 4; mi++) {
                    acc[mi][ni] = __builtin_amdgcn_mfma_f32_16x16x32_bf16(aw[mi], bxh, acc[mi][ni], 0, 0, 0);
                    acc[mi][ni] = __builtin_amdgcn_mfma_f32_16x16x32_bf16(aw[mi], bxl, acc[mi][ni], 0, 0, 0);
                }
            }
        } else {
            bf8_t axh[4], axl[4];
            #pragma unroll
            for (int mi = 0; mi < 4; mi++) {
                axh[mi] = *reinterpret_cast<const bf8_t*>(&XsH[aoff + mi * 16 + l16][quad * 8]);
                axl[mi] = *reinterpret_cast<const bf8_t*>(&XsL[aoff + mi * 16 + l16][quad * 8]);
            }
            #pragma unroll
            for (int ni = 0; ni < 4; ni++) {
                bf8_t bw = *reinterpret_cast<const bf8_t*>(&WsH[boff + ni * 16 + l16][quad * 8]);
                #pragma unroll
                for (int mi = 0; mi < 4; mi++) {
                    acc[mi][ni] = __builtin_amdgcn_mfma_f32_16x16x32_bf16(axh[mi], bw, acc[mi][ni], 0, 0, 0);
                    acc[mi][ni] = __builtin_amdgcn_mfma_f32_16x16x32_bf16(axl[mi], bw, acc[mi][ni], 0, 0, 0);
                }
            }
        }
    }

    if (wsel < 2) {
        float scale = (wsel == 0) ? 0.0625f : 1.0f;  // fold 1/sqrt(d) into q
        unsigned short* dh = (wsel == 0) ? qh : kh;
        #pragma unroll
        for (int mi = 0; mi < 4; mi++) {
            #pragma unroll
            for (int ni = 0; ni < 4; ni++) {
                int e0 = eBase + aoff + mi * 16 + quad * 4;
                size_t row = rowBase + boff + ni * 16 + l16;
                union { unsigned short us[4]; unsigned long long u; } ph, pl;
                #pragma unroll
                for (int rr = 0; rr < 4; rr++) {
                    float x = acc[mi][ni][rr] * scale;
                    unsigned short h = f2bf(x);
                    ph.us[rr] = h;
                    pl.us[rr] = f2bf(x - bf2f(h));
                }
                *reinterpret_cast<unsigned long long*>(&dh[row * D + e0]) = ph.u;
                if (wsel == 0)
                    *reinterpret_cast<unsigned long long*>(&ql[row * D + e0]) = pl.u;
            }
        }
    } else {
        #pragma unroll
        for (int mi = 0; mi < 4; mi++) {
            #pragma unroll
            for (int ni = 0; ni < 4; ni++) {
                int row0 = rowBase + aoff + mi * 16 + quad * 4;
                int e = eBase + boff + ni * 16 + l16;
                int head = row0 >> 10, kb = (row0 & 1023) >> 5, kk = row0 & 31;
                union { unsigned short us[4]; unsigned long long u; } pk;
                #pragma unroll
                for (int rr = 0; rr < 4; rr++) pk.us[rr] = f2bf(acc[mi][ni][rr]);
                *reinterpret_cast<unsigned long long*>(
                    &vt[((size_t)(head * 32 + kb)) * 8192 + (size_t)e * 32 + kk]) = pk.u;
            }
        }
    }
}

// ---------------- key-split MFMA flash attention ---------------------------
// 8 waves/block (2/SIMD), key-split across the wave pair (roles 0/1).
// R2 lesson: occupancy attributes don't stop the scheduler from sinking
// loads to uses (VGPR stayed 120; ~32 serial L2-latency exposures/tile).
// v6: sched_barrier(0) fences pin {K16+V8 batch} | QK | {V8} | softmax|PV.
// Forced liveness ~210 VGPR < 256 budget from launch_bounds(512).
__global__ __launch_bounds__(512) void attn_v6(
    const unsigned short* __restrict__ qh, const unsigned short* __restrict__ ql,
    const unsigned short* __restrict__ kh, const unsigned short* __restrict__ vt,
    float* __restrict__ hout)
{
    __shared__ __align__(16) float comb[4][64 * 68];       // pad 68: conflict-free b128
    __shared__ __align__(16) unsigned short Pb[8][16 * 40];
    __shared__ float ml[4][2][16];

    int tid = threadIdx.x;
    int w = tid >> 6, lane = tid & 63;
    int quad = lane >> 4, l16 = lane & 15;
    int b = blockIdx.x;
    int head = ((b & 7) << 2) + (b >> 6);     // XCD-swizzle: head's 8 blocks share an XCD
    int pg = (b >> 3) & 7;
    int pair = w & 3;
    int role = w >> 2;                         // 0: low keys + combiner; 1: high keys
    int pi = (pg << 2) + pair;                 // pair index 0..31 per head
    size_t hb = (size_t)head * (L * D);
    const unsigned short* vth = vt + (size_t)head * (32 * 8192);
    unsigned short* Pw = Pb[w];
    float* cb = comb[pair];

    #pragma unroll 1
    for (int half = 0; half < 2; half++) {
        int u = half ? (63 - pi) : pi;         // 16-row unit
        int q_g = u * 16 + l16;

        bf8_t qfh[8], qfl[8];
        {
            const unsigned short* ph = qh + hb + (size_t)q_g * D + quad * 8;
            const unsigned short* pl = ql + hb + (size_t)q_g * D + quad * 8;
            #pragma unroll
            for (int c = 0; c < 8; c++) {
                qfh[c] = *reinterpret_cast<const bf8_t*>(ph + c * 32);
                qfl[c] = *reinterpret_cast<const bf8_t*>(pl + c * 32);
            }
        }
        __builtin_amdgcn_sched_barrier(0);     // Q batch stays hoisted & live

        f4_t acc[16];
        #pragma unroll
        for (int i = 0; i < 16; i++) acc[i] = (f4_t){0.f, 0.f, 0.f, 0.f};
        float mrun = -1e30f, lrun = 0.f;

        int n = (u >> 1) + 1;                  // total k-tiles for this unit
        int ktb = role ? (n >> 1) : 0;
        int kte = role ? n : (n >> 1);

        for (int kt = ktb; kt < kte; kt++) {
            int kBase = kt * 32;
            const unsigned short* kp0 = kh + hb + (size_t)(kBase + l16) * D + quad * 8;
            const unsigned short* kp1 = kp0 + 16 * D;
            const unsigned short* vp = vth + (size_t)kt * 8192 + l16 * 32 + quad * 8;

            // ---- load phase: 16 K + 8 V issued as one batch ----
            bf8_t kf0[8], kf1[8], vfA[8];
            #pragma unroll
            for (int c = 0; c < 8; c++) kf0[c] = *reinterpret_cast<const bf8_t*>(kp0 + c * 32);
            #pragma unroll
            for (int c = 0; c < 8; c++) kf1[c] = *reinterpret_cast<const bf8_t*>(kp1 + c * 32);
            #pragma unroll
            for (int dt = 0; dt < 8; dt++)
                vfA[dt] = *reinterpret_cast<const bf8_t*>(vp + dt * 512);
            __builtin_amdgcn_sched_barrier(0);  // nothing sinks below / hoists above

            // ---- QK phase: compiler waits per-fragment, rest stays in flight ----
            f4_t s0a = (f4_t){0.f,0.f,0.f,0.f}, s0b = (f4_t){0.f,0.f,0.f,0.f};
            f4_t s1a = (f4_t){0.f,0.f,0.f,0.f}, s1b = (f4_t){0.f,0.f,0.f,0.f};
            #pragma unroll
            for (int c = 0; c < 8; c += 2) {
                s0a = __builtin_amdgcn_mfma_f32_16x16x32_bf16(kf0[c],     qfh[c],     s0a, 0, 0, 0);
                s0b = __builtin_amdgcn_mfma_f32_16x16x32_bf16(kf0[c + 1], qfh[c + 1], s0b, 0, 0, 0);
                s0a = __builtin_amdgcn_mfma_f32_16x16x32_bf16(kf0[c],     qfl[c],     s0a, 0, 0, 0);
                s0b = __builtin_amdgcn_mfma_f32_16x16x32_bf16(kf0[c + 1], qfl[c + 1], s0b, 0, 0, 0);
            }
            #pragma unroll
            for (int c = 0; c < 8; c += 2) {
                s1a = __builtin_amdgcn_mfma_f32_16x16x32_bf16(kf1[c],     qfh[c],     s1a, 0, 0, 0);
                s1b = __builtin_amdgcn_mfma_f32_16x16x32_bf16(kf1[c + 1], qfh[c + 1], s1b, 0, 0, 0);
                s1a = __builtin_amdgcn_mfma_f32_16x16x32_bf16(kf1[c],     qfl[c],     s1a, 0, 0, 0);
                s1b = __builtin_amdgcn_mfma_f32_16x16x32_bf16(kf1[c + 1], qfl[c + 1], s1b, 0, 0, 0);
            }
            f4_t s[2];
            s[0] = s0a + s0b;
            s[1] = s1a + s1b;
            __builtin_amdgcn_sched_barrier(0);

            // ---- V batch B: in flight across softmax + PV-A ----
            bf8_t vfB[8];
            #pragma unroll
            for (int dt = 0; dt < 8; dt++)
                vfB[dt] = *reinterpret_cast<const bf8_t*>(vp + (8 + dt) * 512);
            __builtin_amdgcn_sched_barrier(0);

            // causal mask + per-lane softmax over 8 keys, quad-pair reduce
            float pv[2][4];
            float tm = -1e30f;
            #pragma unroll
            for (int t = 0; t < 2; t++)
                #pragma unroll
                for (int r = 0; r < 4; r++) {
                    int key = kBase + t * 16 + quad * 4 + r;
                    float sv = (key <= q_g) ? s[t][r] : -1e30f;
                    s[t][r] = sv;
                    tm = fmaxf(tm, sv);
                }
            tm = fmaxf(tm, __shfl_xor(tm, 16));
            tm = fmaxf(tm, __shfl_xor(tm, 32));
            bool grow = __any(tm > mrun);      // wave-uniform; alpha==1 exactly if false
            float mnew = fmaxf(mrun, tm);
            float alpha = grow ? __expf(mrun - mnew) : 1.0f;
            mrun = mnew;
            float ts = 0.f;
            #pragma unroll
            for (int t = 0; t < 2; t++)
                #pragma unroll
                for (int r = 0; r < 4; r++) {
                    float p = __expf(s[t][r] - mnew);
                    pv[t][r] = p;
                    ts += p;
                }
            ts += __shfl_xor(ts, 16);
            ts += __shfl_xor(ts, 32);
            lrun = lrun * alpha + ts;

            // P write issued BEFORE the O-rescale: LDS round-trip hides
            // under the 64 rescale muls (or under nothing when skipped).
            #pragma unroll
            for (int t = 0; t < 2; t++) {
                union { unsigned short us[4]; unsigned long long u; } pk;
                #pragma unroll
                for (int r = 0; r < 4; r++) pk.us[r] = f2bf(pv[t][r]);
                *reinterpret_cast<unsigned long long*>(&Pw[l16 * 40 + t * 16 + quad * 4]) = pk.u;
            }
            if (grow) {
                #pragma unroll
                for (int dt = 0; dt < 16; dt++) acc[dt] *= alpha;
            }
            asm volatile("s_waitcnt lgkmcnt(0)" ::: "memory");
            __builtin_amdgcn_sched_barrier(0);
            bf8_t pf = *reinterpret_cast<const bf8_t*>(&Pw[l16 * 40 + quad * 8]);
            #pragma unroll
            for (int dt = 0; dt < 8; dt++)
                acc[dt] = __builtin_amdgcn_mfma_f32_16x16x32_bf16(vfA[dt], pf, acc[dt], 0, 0, 0);
            #pragma unroll
            for (int dt = 0; dt < 8; dt++)
                acc[8 + dt] = __builtin_amdgcn_mfma_f32_16x16x32_bf16(vfB[dt], pf, acc[8 + dt], 0, 0, 0);
        }

        // ---- combine the two partial halves of this unit ----
        if (role) {
            #pragma unroll
            for (int dt = 0; dt < 16; dt++)
                *reinterpret_cast<f4_t*>(cb + lane * 68 + dt * 4) = acc[dt];
            if (quad == 0) { ml[pair][0][l16] = mrun; ml[pair][1][l16] = lrun; }
        }
        __syncthreads();
        if (!role) {
            float mB = ml[pair][0][l16], lB = ml[pair][1][l16];
            float m = fmaxf(mrun, mB);
            float sa = __expf(mrun - m);
            float sb = __expf(mB - m);
            float inv = 1.f / (lrun * sa + lB * sb);
            float* dst = hout + hb + (size_t)q_g * D + quad * 4;
            #pragma unroll
            for (int dt = 0; dt < 16; dt++) {
                f4_t ob = *reinterpret_cast<f4_t*>(cb + lane * 68 + dt * 4);
                float4 o = {(acc[dt][0] * sa + ob[0] * sb) * inv,
                            (acc[dt][1] * sa + ob[1] * sb) * inv,
                            (acc[dt][2] * sa + ob[2] * sb) * inv,
                            (acc[dt][3] * sa + ob[3] * sb) * inv};
                *reinterpret_cast<float4*>(dst + dt * 16) = o;
            }
        }
        __syncthreads();   // protect comb reuse for the next half
    }
}

// ---------------- equivariant path: one wave per q row ---------------------
__global__ __launch_bounds__(256) void equiv_kernel(
    const float* __restrict__ xsb, float* __restrict__ xout)
{
    __shared__ float xs[L * NCH];
    int head = blockIdx.y;
    int tid = threadIdx.x;
    const float4* src = reinterpret_cast<const float4*>(xsb + (size_t)head * L * NCH);
    #pragma unroll
    for (int it = 0; it < 3; it++)
        reinterpret_cast<float4*>(xs)[tid + it * 256] = src[tid + it * 256];
    __syncthreads();

    int w = tid >> 6, lane = tid & 63;
    int q = blockIdx.x * 4 + w;
    float xq0 = xs[q * 3 + 0], xq1 = xs[q * 3 + 1], xq2 = xs[q * 3 + 2];

    float m = 0.f;
    for (int k = lane; k < q; k += 64) {
        float d0 = xq0 - xs[k * 3 + 0];
        float d1 = xq1 - xs[k * 3 + 1];
        float d2 = xq2 - xs[k * 3 + 2];
        m = fmaxf(m, d0 * d0 + d1 * d1 + d2 * d2);
    }
    #pragma unroll
    for (int off = 1; off < 64; off <<= 1) m = fmaxf(m, __shfl_xor(m, off));

    float s0 = 0.f, s1 = 0.f, s2 = 0.f, sn = 0.f;
    for (int k = lane; k < q; k += 64) {
        float d0 = xq0 - xs[k * 3 + 0];
        float d1 = xq1 - xs[k * 3 + 1];
        float d2 = xq2 - xs[k * 3 + 2];
        float wgt = __expf(d0 * d0 + d1 * d1 + d2 * d2 - m);
        sn += wgt;
        s0 += wgt * xs[k * 3 + 0];
        s1 += wgt * xs[k * 3 + 1];
        s2 += wgt * xs[k * 3 + 2];
    }
    #pragma unroll
    for (int off = 1; off < 64; off <<= 1) {
        sn += __shfl_xor(sn, off);
        s0 += __shfl_xor(s0, off);
        s1 += __shfl_xor(s1, off);
        s2 += __shfl_xor(s2, off);
    }
    float Z = sn + __expf(-m);
    float inv = 0.5f / Z;
    if (lane == 0) {
        size_t ob = (size_t)head * L * NCH + (size_t)q * NCH;
        xout[ob + 0] = xq0 + inv * (s0 - sn * xq0);
        xout[ob + 1] = xq1 + inv * (s1 - sn * xq1);
        xout[ob + 2] = xq2 + inv * (s2 - sn * xq2);
    }
}

extern "C" void kernel_launch(void* const* d_in, const int* in_sizes, int n_in,
                              void* d_out, int out_size, void* d_ws, size_t ws_size,
                              hipStream_t stream)
{
    (void)in_sizes; (void)n_in; (void)out_size; (void)ws_size;
    const float* theta = (const float*)d_in[0];
    const float* xi    = (const float*)d_in[1];
    const float* edge  = (const float*)d_in[2];
    const float* Wq    = (const float*)d_in[3];
    const float* Wk    = (const float*)d_in[4];
    const float* Wv    = (const float*)d_in[5];

    float* out  = (float*)d_out;
    float* hout = out;
    float* xout = out + 8388608;
    float* eout = out + 8388608 + 98304;

    const size_t NE = 8388608;
    unsigned short* base = (unsigned short*)d_ws;
    unsigned short* qh = base;
    unsigned short* ql = base + NE;
    unsigned short* kh = base + 2 * NE;
    unsigned short* vt = base + 3 * NE;
    float* pe_d = (float*)(base + 4 * NE);           // 1024*256 floats
    float* xsb  = pe_d + L * D;                       // 32*1024*3 floats

    prep_kernel<<<3200, 256, 0, stream>>>(edge, xi, pe_d, eout, xsb);
    equiv_kernel<<<dim3(L / 4, HEADS), 256, 0, stream>>>(xsb, xout);
    qkv_mfma<<<1536, 256, 0, stream>>>(theta, pe_d, Wq, Wk, Wv, qh, ql, kh, vt);
    attn_v6<<<256, 512, 0, stream>>>(qh, ql, kh, vt, hout);
}

// Round 4
// 236.986 us; speedup vs baseline: 1.1775x; 1.1775x over previous
//
#include <hip/hip_runtime.h>
#include <math.h>

#define L    1024
#define D    256
#define NCH  3
#define HEADS 32      // B*N
#define EDIM 112
#define BATCH 4

typedef __bf16 bf8_t __attribute__((ext_vector_type(8)));
typedef float  f4_t  __attribute__((ext_vector_type(4)));

typedef __attribute__((address_space(1))) const void GVC;
typedef __attribute__((address_space(3))) void LDSV;

// RNE float->bf16
__device__ inline unsigned short f2bf(float x) {
    unsigned u = __float_as_uint(x);
    u += 0x7FFFu + ((u >> 16) & 1u);
    return (unsigned short)(u >> 16);
}
__device__ inline float bf2f(unsigned short h) {
    return __uint_as_float(((unsigned)h) << 16);
}

// ---------------- fused prologue: pe_d + edge + xs -------------------------
__global__ void prep_kernel(const float* __restrict__ edge, const float* __restrict__ xi,
                            float* __restrict__ pe_d, float* __restrict__ eout,
                            float* __restrict__ xsb)
{
    int idx = blockIdx.x * blockDim.x + threadIdx.x;
    if (idx < L * D) {
        int l = idx >> 8, i = idx & (D - 1);
        float expo = (float)(i & ~1) * (1.0f / (float)D);
        float ang = (float)l * __powf(10000.0f, -expo);
        pe_d[idx] = (i & 1) ? cosf(ang) : sinf(ang);
    } else if (idx < L * D + BATCH * L * EDIM) {
        int j = idx - L * D;
        int i = j % EDIM;
        int l = (j / EDIM) % L;
        float expo = (float)(i & ~1) * (1.0f / (float)EDIM);
        float ang = (float)l * __powf(10000.0f, -expo);
        eout[j] = edge[j] + ((i & 1) ? cosf(ang) : sinf(ang));
    } else {
        int j = idx - (L * D + BATCH * L * EDIM);
        if (j < HEADS * L * NCH) {
            int c = j % 3;
            int l = (j / 3) & (L - 1);
            float ang = (c == 2) ? (float)l * 0.0021544347f : (float)l;  // 10000^(-2/3)
            float pe = (c == 1) ? cosf(ang) : sinf(ang);
            xsb[j] = xi[j] + pe;
        }
    }
}

// ---------------- QKV projection via split-bf16 MFMA (2-term) --------------
// kh is stored PRE-SWIZZLED (e ^= (row&7)*8) and vt PRE-SWIZZLED
// (us ^= ((e>>1)&3)*8) so that attn's linear global_load_lds staging lands a
// bank-conflict-free LDS layout (swizzle applied again on the ds_read side).
__global__ __launch_bounds__(256) void qkv_mfma(
    const float* __restrict__ theta, const float* __restrict__ pe_d,
    const float* __restrict__ Wq, const float* __restrict__ Wk, const float* __restrict__ Wv,
    unsigned short* __restrict__ qh, unsigned short* __restrict__ ql,
    unsigned short* __restrict__ kh, unsigned short* __restrict__ vt)
{
    __shared__ unsigned short XsH[128][40], XsL[128][40], WsH[128][40];

    int tid = threadIdx.x;
    int w = tid >> 6, lane = tid & 63;
    int quad = lane >> 4, l16 = lane & 15;
    int aoff = (w & 1) * 64, boff = (w >> 1) * 64;

    int b = blockIdx.x;                 // 0..1535
    int xcd = b & 7, r = b >> 3;        // r in 0..191
    int bx = r % 6;                     // selector (wsel, eBase)
    int rowPanel = (r / 6) * 8 + xcd;   // 0..255, all 6 bx of a panel share xcd
    int rowBase = rowPanel * 128;
    int wsel = bx >> 1;
    int eBase = (bx & 1) * 128;
    const float* W = (wsel == 0) ? Wq : (wsel == 1) ? Wk : Wv;

    f4_t acc[4][4];
    #pragma unroll
    for (int mi = 0; mi < 4; mi++)
        #pragma unroll
        for (int ni = 0; ni < 4; ni++) acc[mi][ni] = (f4_t){0.f, 0.f, 0.f, 0.f};

    int sr = tid >> 1;
    int ks = (tid & 1) * 16;

    for (int kt = 0; kt < 8; kt++) {
        int k0 = kt * 32 + ks;
        __syncthreads();
        {
            union { unsigned short us[16]; float4 f4[2]; } hi, lo;
            const float* tp = &theta[(size_t)(rowBase + sr) * D + k0];
            const float* pp = &pe_d[(size_t)((rowBase + sr) & (L - 1)) * D + k0];
            #pragma unroll
            for (int j = 0; j < 4; j++) {
                float4 tv = reinterpret_cast<const float4*>(tp)[j];
                float4 pv = reinterpret_cast<const float4*>(pp)[j];
                float xs[4] = {tv.x + pv.x, tv.y + pv.y, tv.z + pv.z, tv.w + pv.w};
                #pragma unroll
                for (int q = 0; q < 4; q++) {
                    unsigned short h = f2bf(xs[q]);
                    hi.us[j * 4 + q] = h;
                    lo.us[j * 4 + q] = f2bf(xs[q] - bf2f(h));
                }
            }
            *reinterpret_cast<float4*>(&XsH[sr][ks]) = hi.f4[0];
            *reinterpret_cast<float4*>(&XsH[sr][ks + 8]) = hi.f4[1];
            *reinterpret_cast<float4*>(&XsL[sr][ks]) = lo.f4[0];
            *reinterpret_cast<float4*>(&XsL[sr][ks + 8]) = lo.f4[1];

            const float* wp = &W[(size_t)(eBase + sr) * D + k0];
            #pragma unroll
            for (int j = 0; j < 4; j++) {
                float4 wv = reinterpret_cast<const float4*>(wp)[j];
                float xs[4] = {wv.x, wv.y, wv.z, wv.w};
                #pragma unroll
                for (int q = 0; q < 4; q++) hi.us[j * 4 + q] = f2bf(xs[q]);
            }
            *reinterpret_cast<float4*>(&WsH[sr][ks]) = hi.f4[0];
            *reinterpret_cast<float4*>(&WsH[sr][ks + 8]) = hi.f4[1];
        }
        __syncthreads();

        if (wsel < 2) {
            bf8_t aw[4];
            #pragma unroll
            for (int mi = 0; mi < 4; mi++)
                aw[mi] = *reinterpret_cast<const bf8_t*>(&WsH[aoff + mi * 16 + l16][quad * 8]);
            #pragma unroll
            for (int ni = 0; ni < 4; ni++) {
                bf8_t bxh = *reinterpret_cast<const bf8_t*>(&XsH[boff + ni * 16 + l16][quad * 8]);
                bf8_t bxl = *reinterpret_cast<const bf8_t*>(&XsL[boff + ni * 16 + l16][quad * 8]);
                #pragma unroll
                for (int mi = 0; mi < 4; mi++) {
                    acc[mi][ni] = __builtin_amdgcn_mfma_f32_16x16x32_bf16(aw[mi], bxh, acc[mi][ni], 0, 0, 0);
                    acc[mi][ni] = __builtin_amdgcn_mfma_f32_16x16x32_bf16(aw[mi], bxl, acc[mi][ni], 0, 0, 0);
                }
            }
        } else {
            bf8_t axh[4], axl[4];
            #pragma unroll
            for (int mi = 0; mi < 4; mi++) {
                axh[mi] = *reinterpret_cast<const bf8_t*>(&XsH[aoff + mi * 16 + l16][quad * 8]);
                axl[mi] = *reinterpret_cast<const bf8_t*>(&XsL[aoff + mi * 16 + l16][quad * 8]);
            }
            #pragma unroll
            for (int ni = 0; ni < 4; ni++) {
                bf8_t bw = *reinterpret_cast<const bf8_t*>(&WsH[boff + ni * 16 + l16][quad * 8]);
                #pragma unroll
                for (int mi = 0; mi < 4; mi++) {
                    acc[mi][ni] = __builtin_amdgcn_mfma_f32_16x16x32_bf16(axh[mi], bw, acc[mi][ni], 0, 0, 0);
                    acc[mi][ni] = __builtin_amdgcn_mfma_f32_16x16x32_bf16(axl[mi], bw, acc[mi][ni], 0, 0, 0);
                }
            }
        }
    }

    if (wsel < 2) {
        float scale = (wsel == 0) ? 0.0625f : 1.0f;  // fold 1/sqrt(d) into q
        #pragma unroll
        for (int mi = 0; mi < 4; mi++) {
            #pragma unroll
            for (int ni = 0; ni < 4; ni++) {
                int e0 = eBase + aoff + mi * 16 + quad * 4;
                size_t row = rowBase + boff + ni * 16 + l16;
                union { unsigned short us[4]; unsigned long long u; } ph, pl;
                #pragma unroll
                for (int rr = 0; rr < 4; rr++) {
                    float x = acc[mi][ni][rr] * scale;
                    unsigned short h = f2bf(x);
                    ph.us[rr] = h;
                    pl.us[rr] = f2bf(x - bf2f(h));
                }
                if (wsel == 0) {
                    *reinterpret_cast<unsigned long long*>(&qh[row * D + e0]) = ph.u;
                    *reinterpret_cast<unsigned long long*>(&ql[row * D + e0]) = pl.u;
                } else {
                    int e0s = e0 ^ ((l16 & 7) << 3);   // row&7 == l16&7
                    *reinterpret_cast<unsigned long long*>(&kh[row * D + e0s]) = ph.u;
                }
            }
        }
    } else {
        #pragma unroll
        for (int mi = 0; mi < 4; mi++) {
            #pragma unroll
            for (int ni = 0; ni < 4; ni++) {
                int row0 = rowBase + aoff + mi * 16 + quad * 4;
                int e = eBase + boff + ni * 16 + l16;
                int head = row0 >> 10, kb = (row0 & 1023) >> 5, kk = row0 & 31;
                union { unsigned short us[4]; unsigned long long u; } pk;
                #pragma unroll
                for (int rr = 0; rr < 4; rr++) pk.us[rr] = f2bf(acc[mi][ni][rr]);
                int us_sw = (e * 32 + kk) ^ (((e >> 1) & 3) << 3);  // V-tile swizzle
                *reinterpret_cast<unsigned long long*>(
                    &vt[((size_t)(head * 32 + kb)) * 8192 + us_sw]) = pk.u;
            }
        }
    }
}

// ---------------- LDS-shared MFMA flash attention --------------------------
// R3 diagnosis: v3-v6 all ~110us because time ∝ total wave-tiles (33.8k x
// 32KB = 1.08GB of L2/L3 fabric traffic = ~9.6 TB/s ceiling). v7 shares each
// K/V tile across the block's 8 waves via LDS (global_load_lds staging,
// double-buffered): fabric traffic /5, becomes LDS-BW bound (~15-20us floor).
// Block (head,s): 8 mirrored units {4s..4s+3, 63-4s..60-4s} -> uniform
// ~128 wave-tile computes/block; stages Ts = 32-2s tiles.
__device__ __forceinline__ void stage_tile(
    const unsigned short* kht, const unsigned short* vtt,
    unsigned short* Ks, unsigned short* Vs, int kt, int buf, int w, int lane)
{
    #pragma unroll
    for (int i = 0; i < 2; i++) {
        int ch = w * 2 + i;   // wave-uniform chunk id (LDS base must be uniform)
        __builtin_amdgcn_global_load_lds(
            (GVC*)(kht + (size_t)kt * 8192 + ch * 512 + lane * 8),
            (LDSV*)(Ks + buf * 8192 + ch * 512), 16, 0, 0);
        __builtin_amdgcn_global_load_lds(
            (GVC*)(vtt + (size_t)kt * 8192 + ch * 512 + lane * 8),
            (LDSV*)(Vs + buf * 8192 + ch * 512), 16, 0, 0);
    }
}

__global__ __launch_bounds__(512) void attn_v7(
    const unsigned short* __restrict__ qh, const unsigned short* __restrict__ ql,
    const unsigned short* __restrict__ kh, const unsigned short* __restrict__ vt,
    float* __restrict__ hout)
{
    __shared__ __align__(16) unsigned short Ks[2 * 8192];   // 32KB K dbuf
    __shared__ __align__(16) unsigned short Vs[2 * 8192];   // 32KB V dbuf
    __shared__ __align__(16) unsigned short Pb[8][16 * 40]; // 10KB P
    __shared__ unsigned short lds_pad[4200];                // >80KB: 1 block/CU

    int tid = threadIdx.x;
    int w = tid >> 6, lane = tid & 63;
    int quad = lane >> 4, l16 = lane & 15;
    int b = blockIdx.x;
    int head = ((b & 7) << 2) + (b >> 6);     // 4 heads per XCD share L2
    int s = (b >> 3) & 7;
    int u = (w < 4) ? (4 * s + w) : (63 - 4 * s - (w - 4));  // mirrored units
    int Ts = 32 - 2 * s;
    int lim = u >> 1;
    size_t hb = (size_t)head * (L * D);
    const unsigned short* kht = kh + hb;
    const unsigned short* vtt = vt + (size_t)head * (32 * 8192);
    unsigned short* Pw = Pb[w];

    if (hout == nullptr) lds_pad[tid] = 1;    // opaque: keep pad allocated

    int q_g = u * 16 + l16;

    // Q fragments in registers for the whole kernel; asm keep-alive stops
    // the scheduler from sinking/re-fetching them inside the k-loop.
    f4_t qfh[8], qfl[8];
    {
        const unsigned short* ph = qh + hb + (size_t)q_g * D + quad * 8;
        const unsigned short* pl = ql + hb + (size_t)q_g * D + quad * 8;
        #pragma unroll
        for (int c = 0; c < 8; c++) {
            qfh[c] = *reinterpret_cast<const f4_t*>(ph + c * 32);
            qfl[c] = *reinterpret_cast<const f4_t*>(pl + c * 32);
        }
    }
    #pragma unroll
    for (int c = 0; c < 8; c++) {
        asm volatile("" : "+v"(qfh[c]));
        asm volatile("" : "+v"(qfl[c]));
    }

    stage_tile(kht, vtt, Ks, Vs, 0, 0, w, lane);

    f4_t acc[16];
    #pragma unroll
    for (int i = 0; i < 16; i++) acc[i] = (f4_t){0.f, 0.f, 0.f, 0.f};
    float mrun = -1e30f, lrun = 0.f;

    int xm = (l16 & 7) << 3;                        // K e-swizzle (us)
    int vq = (quad * 8) ^ (((l16 >> 1) & 3) << 3);  // V swizzled col base

    asm volatile("s_waitcnt vmcnt(0)" ::: "memory");
    __syncthreads();

    #pragma unroll 1
    for (int kt = 0; kt < Ts; kt++) {
        if (kt + 1 < Ts)
            stage_tile(kht, vtt, Ks, Vs, kt + 1, (kt + 1) & 1, w, lane);

        if (kt <= lim) {   // wave-uniform predicate
            const unsigned short* Kb = Ks + (kt & 1) * 8192;
            const unsigned short* Vb = Vs + (kt & 1) * 8192;
            int kBase = kt * 32;

            bf8_t kf0[8], kf1[8];
            #pragma unroll
            for (int c = 0; c < 8; c++) {
                int col = (quad * 8 + c * 32) ^ xm;
                kf0[c] = *reinterpret_cast<const bf8_t*>(&Kb[l16 * 256 + col]);
                kf1[c] = *reinterpret_cast<const bf8_t*>(&Kb[(16 + l16) * 256 + col]);
            }
            // V batch A: LDS-read latency hides under the QK MFMAs
            const unsigned short* vpb = Vb + l16 * 32 + vq;
            bf8_t vfA[8];
            #pragma unroll
            for (int dt = 0; dt < 8; dt++)
                vfA[dt] = *reinterpret_cast<const bf8_t*>(vpb + dt * 512);

            // dual accumulator chains: halves dependent-MFMA depth
            f4_t s0a = (f4_t){0.f,0.f,0.f,0.f}, s0b = (f4_t){0.f,0.f,0.f,0.f};
            f4_t s1a = (f4_t){0.f,0.f,0.f,0.f}, s1b = (f4_t){0.f,0.f,0.f,0.f};
            #pragma unroll
            for (int c = 0; c < 8; c += 2) {
                s0a = __builtin_amdgcn_mfma_f32_16x16x32_bf16(kf0[c],     __builtin_bit_cast(bf8_t, qfh[c]),     s0a, 0, 0, 0);
                s0b = __builtin_amdgcn_mfma_f32_16x16x32_bf16(kf0[c + 1], __builtin_bit_cast(bf8_t, qfh[c + 1]), s0b, 0, 0, 0);
                s0a = __builtin_amdgcn_mfma_f32_16x16x32_bf16(kf0[c],     __builtin_bit_cast(bf8_t, qfl[c]),     s0a, 0, 0, 0);
                s0b = __builtin_amdgcn_mfma_f32_16x16x32_bf16(kf0[c + 1], __builtin_bit_cast(bf8_t, qfl[c + 1]), s0b, 0, 0, 0);
            }
            #pragma unroll
            for (int c = 0; c < 8; c += 2) {
                s1a = __builtin_amdgcn_mfma_f32_16x16x32_bf16(kf1[c],     __builtin_bit_cast(bf8_t, qfh[c]),     s1a, 0, 0, 0);
                s1b = __builtin_amdgcn_mfma_f32_16x16x32_bf16(kf1[c + 1], __builtin_bit_cast(bf8_t, qfh[c + 1]), s1b, 0, 0, 0);
                s1a = __builtin_amdgcn_mfma_f32_16x16x32_bf16(kf1[c],     __builtin_bit_cast(bf8_t, qfl[c]),     s1a, 0, 0, 0);
                s1b = __builtin_amdgcn_mfma_f32_16x16x32_bf16(kf1[c + 1], __builtin_bit_cast(bf8_t, qfl[c + 1]), s1b, 0, 0, 0);
            }
            f4_t sc[2];
            sc[0] = s0a + s0b;
            sc[1] = s1a + s1b;

            // causal mask + per-lane softmax over 8 keys, quad-pair reduce
            float pv[2][4];
            float tm = -1e30f;
            #pragma unroll
            for (int t = 0; t < 2; t++)
                #pragma unroll
                for (int rr = 0; rr < 4; rr++) {
                    int key = kBase + t * 16 + quad * 4 + rr;
                    float sv = (key <= q_g) ? sc[t][rr] : -1e30f;
                    sc[t][rr] = sv;
                    tm = fmaxf(tm, sv);
                }
            tm = fmaxf(tm, __shfl_xor(tm, 16));
            tm = fmaxf(tm, __shfl_xor(tm, 32));
            bool grow = __any(tm > mrun);      // alpha==1 exactly if false
            float mnew = fmaxf(mrun, tm);
            float alpha = grow ? __expf(mrun - mnew) : 1.0f;
            mrun = mnew;
            float ts = 0.f;
            #pragma unroll
            for (int t = 0; t < 2; t++)
                #pragma unroll
                for (int rr = 0; rr < 4; rr++) {
                    float p = __expf(sc[t][rr] - mnew);
                    pv[t][rr] = p;
                    ts += p;
                }
            ts += __shfl_xor(ts, 16);
            ts += __shfl_xor(ts, 32);
            lrun = lrun * alpha + ts;

            // P write before O-rescale: LDS round-trip hides under the muls
            #pragma unroll
            for (int t = 0; t < 2; t++) {
                union { unsigned short us[4]; unsigned long long uu; } pk;
                #pragma unroll
                for (int rr = 0; rr < 4; rr++) pk.us[rr] = f2bf(pv[t][rr]);
                *reinterpret_cast<unsigned long long*>(&Pw[l16 * 40 + t * 16 + quad * 4]) = pk.uu;
            }
            // V batch B
            bf8_t vfB[8];
            #pragma unroll
            for (int dt = 0; dt < 8; dt++)
                vfB[dt] = *reinterpret_cast<const bf8_t*>(vpb + (8 + dt) * 512);
            if (grow) {
                #pragma unroll
                for (int dt = 0; dt < 16; dt++) acc[dt] *= alpha;
            }
            asm volatile("s_waitcnt lgkmcnt(0)" ::: "memory");
            bf8_t pf = *reinterpret_cast<const bf8_t*>(&Pw[l16 * 40 + quad * 8]);
            #pragma unroll
            for (int dt = 0; dt < 8; dt++)
                acc[dt] = __builtin_amdgcn_mfma_f32_16x16x32_bf16(vfA[dt], pf, acc[dt], 0, 0, 0);
            #pragma unroll
            for (int dt = 0; dt < 8; dt++)
                acc[8 + dt] = __builtin_amdgcn_mfma_f32_16x16x32_bf16(vfB[dt], pf, acc[8 + dt], 0, 0, 0);
        }

        asm volatile("s_waitcnt vmcnt(0)" ::: "memory");
        __syncthreads();
    }

    float inv = 1.f / lrun;
    float* dst = hout + hb + (size_t)q_g * D + quad * 4;
    #pragma unroll
    for (int dt = 0; dt < 16; dt++) {
        float4 o = {acc[dt][0] * inv, acc[dt][1] * inv,
                    acc[dt][2] * inv, acc[dt][3] * inv};
        *reinterpret_cast<float4*>(dst + dt * 16) = o;
    }
}

// ---------------- equivariant path: one wave per q row ---------------------
__global__ __launch_bounds__(256) void equiv_kernel(
    const float* __restrict__ xsb, float* __restrict__ xout)
{
    __shared__ float xs[L * NCH];
    int head = blockIdx.y;
    int tid = threadIdx.x;
    const float4* src = reinterpret_cast<const float4*>(xsb + (size_t)head * L * NCH);
    #pragma unroll
    for (int it = 0; it < 3; it++)
        reinterpret_cast<float4*>(xs)[tid + it * 256] = src[tid + it * 256];
    __syncthreads();

    int w = tid >> 6, lane = tid & 63;
    int q = blockIdx.x * 4 + w;
    float xq0 = xs[q * 3 + 0], xq1 = xs[q * 3 + 1], xq2 = xs[q * 3 + 2];

    float m = 0.f;
    for (int k = lane; k < q; k += 64) {
        float d0 = xq0 - xs[k * 3 + 0];
        float d1 = xq1 - xs[k * 3 + 1];
        float d2 = xq2 - xs[k * 3 + 2];
        m = fmaxf(m, d0 * d0 + d1 * d1 + d2 * d2);
    }
    #pragma unroll
    for (int off = 1; off < 64; off <<= 1) m = fmaxf(m, __shfl_xor(m, off));

    float s0 = 0.f, s1 = 0.f, s2 = 0.f, sn = 0.f;
    for (int k = lane; k < q; k += 64) {
        float d0 = xq0 - xs[k * 3 + 0];
        float d1 = xq1 - xs[k * 3 + 1];
        float d2 = xq2 - xs[k * 3 + 2];
        float wgt = __expf(d0 * d0 + d1 * d1 + d2 * d2 - m);
        sn += wgt;
        s0 += wgt * xs[k * 3 + 0];
        s1 += wgt * xs[k * 3 + 1];
        s2 += wgt * xs[k * 3 + 2];
    }
    #pragma unroll
    for (int off = 1; off < 64; off <<= 1) {
        sn += __shfl_xor(sn, off);
        s0 += __shfl_xor(s0, off);
        s1 += __shfl_xor(s1, off);
        s2 += __shfl_xor(s2, off);
    }
    float Z = sn + __expf(-m);
    float inv = 0.5f / Z;
    if (lane == 0) {
        size_t ob = (size_t)head * L * NCH + (size_t)q * NCH;
        xout[ob + 0] = xq0 + inv * (s0 - sn * xq0);
        xout[ob + 1] = xq1 + inv * (s1 - sn * xq1);
        xout[ob + 2] = xq2 + inv * (s2 - sn * xq2);
    }
}

extern "C" void kernel_launch(void* const* d_in, const int* in_sizes, int n_in,
                              void* d_out, int out_size, void* d_ws, size_t ws_size,
                              hipStream_t stream)
{
    (void)in_sizes; (void)n_in; (void)out_size; (void)ws_size;
    const float* theta = (const float*)d_in[0];
    const float* xi    = (const float*)d_in[1];
    const float* edge  = (const float*)d_in[2];
    const float* Wq    = (const float*)d_in[3];
    const float* Wk    = (const float*)d_in[4];
    const float* Wv    = (const float*)d_in[5];

    float* out  = (float*)d_out;
    float* hout = out;
    float* xout = out + 8388608;
    float* eout = out + 8388608 + 98304;

    const size_t NE = 8388608;
    unsigned short* base = (unsigned short*)d_ws;
    unsigned short* qh = base;
    unsigned short* ql = base + NE;
    unsigned short* kh = base + 2 * NE;
    unsigned short* vt = base + 3 * NE;
    float* pe_d = (float*)(base + 4 * NE);           // 1024*256 floats
    float* xsb  = pe_d + L * D;                       // 32*1024*3 floats

    prep_kernel<<<3200, 256, 0, stream>>>(edge, xi, pe_d, eout, xsb);
    equiv_kernel<<<dim3(L / 4, HEADS), 256, 0, stream>>>(xsb, xout);
    qkv_mfma<<<1536, 256, 0, stream>>>(theta, pe_d, Wq, Wk, Wv, qh, ql, kh, vt);
    attn_v7<<<256, 512, 0, stream>>>(qh, ql, kh, vt, hout);
}